// Round 7
// baseline (107.193 us; speedup 1.0000x reference)
//
#include <hip/hip_runtime.h>
#include <math.h>

// Problem constants
#define B_ 16
#define L_ 512
#define F_ 384
#define H_ 384
#define K_ 3
#define MAX_OUT_ 4096
#define EPS_ 1e-5f

#define M_TOTAL (B_ * L_)             // 8192 gemm rows
#define KDIM (K_ * F_)                // 1152 gemm K
#define NMB 128                       // 64-row blocks (8192/64)
#define NCG 6                         // 64-col groups (384/64)
#define NST 36                        // K-steps of 32 (1152/32)
// Apack: [m(128)][fstep(12)][row(66)][64B]  (row r -> global l = m*64 + r - 1)
#define APANEL (66 * 64)              // bytes per fstep panel = 4224
#define AMBLK (12 * APANEL)           // bytes per m block = 50688
#define APLANE (NMB * AMBLK)          // 6488064 B per plane
// Bpack: [cg(6)][step(36)][row(64)][64B]
#define BSTEP 4096
#define BCG (NST * BSTEP)             // 147456
#define BPLANE (NCG * BCG)            // 884736 B per plane

typedef __attribute__((ext_vector_type(8))) short bf16x8;   // 8 bf16 = 4 VGPR
typedef __attribute__((ext_vector_type(4))) float f32x4;

// ---------------------------------------------------------------------------
// bf16 split helpers: v = hi + lo with RNE rounding (3-term product error ~2^-17)
// ---------------------------------------------------------------------------
__device__ inline unsigned short bf16_rne(float v) {
    unsigned int u = __float_as_uint(v);
    unsigned int r = (u + 0x7fffu + ((u >> 16) & 1u)) >> 16;
    return (unsigned short)r;
}
__device__ inline void bf16_split(float v, unsigned short& hi, unsigned short& lo) {
    hi = bf16_rne(v);
    float hf = __uint_as_float(((unsigned int)hi) << 16);
    lo = bf16_rne(v - hf);
}

// ---------------------------------------------------------------------------
// Kernel 1: per-batch cumsum of target + searchsorted index table (unchanged).
// ---------------------------------------------------------------------------
__global__ void k_scan_idx(const int* __restrict__ target, int* __restrict__ idx) {
    __shared__ int e[L_];
    const int b = blockIdx.x;
    const int tid = threadIdx.x;   // blockDim = 512 = L_
    e[tid] = target[b * L_ + tid];
    __syncthreads();
    for (int off = 1; off < L_; off <<= 1) {
        int add = (tid >= off) ? e[tid - off] : 0;
        __syncthreads();
        e[tid] += add;
        __syncthreads();
    }
    const int total = e[L_ - 1];
    for (int t = tid; t < MAX_OUT_; t += L_) {
        int lo = 0, hi = L_;
        while (lo < hi) {
            int m = (lo + hi) >> 1;
            if (e[m] <= t) lo = m + 1; else hi = m;
        }
        int v = (t < total) ? min(lo, L_ - 1) : -1;
        idx[b * MAX_OUT_ + t] = v;
    }
}

// ---------------------------------------------------------------------------
// Kernel 2: prep — build LANE-CONTIGUOUS packed operand panels (the LDS image)
// so every k_gemm stage/fragment access is a contiguous 1KB wave access.
// Chunk permutation p_store = chunk ^ ((row>>1)&3) baked in.
// ---------------------------------------------------------------------------
__global__ void k_prep(const float* __restrict__ x,
                       const float* __restrict__ w1, const float* __restrict__ w2,
                       unsigned short* __restrict__ aph, unsigned short* __restrict__ apl,
                       unsigned short* __restrict__ b1h, unsigned short* __restrict__ b1l,
                       unsigned short* __restrict__ b2h, unsigned short* __restrict__ b2l) {
    const int NA8 = NMB * 12 * 66 * 4;     // 405504 A chunks (16B each)
    const int NB8 = NCG * NST * 64 * 4;    // 55296 B chunks per conv
    const int total = NA8 + 2 * NB8;
    for (int i = blockIdx.x * blockDim.x + threadIdx.x; i < total;
         i += gridDim.x * blockDim.x) {
        if (i < NA8) {
            const int m = i / 3168;            // 12*66*4
            int r1 = i - m * 3168;
            const int fs = r1 / 264;           // 66*4
            int r2 = r1 - fs * 264;
            const int rp = r2 >> 2;
            const int p = r2 & 3;
            const int cgk = p ^ ((rp >> 1) & 3);
            const int f0 = fs * 32 + cgk * 8;
            const int ll = ((m & 7) << 6) + rp - 1;
            ushort4 h0 = {0,0,0,0}, h1 = {0,0,0,0}, l0 = {0,0,0,0}, l1 = {0,0,0,0};
            if (ll >= 0 && ll < L_) {
                const float* src = x + ((size_t)((m >> 3) * L_ + ll) * F_ + f0);
                float4 va = ((const float4*)src)[0];
                float4 vb = ((const float4*)src)[1];
                bf16_split(va.x, h0.x, l0.x); bf16_split(va.y, h0.y, l0.y);
                bf16_split(va.z, h0.z, l0.z); bf16_split(va.w, h0.w, l0.w);
                bf16_split(vb.x, h1.x, l1.x); bf16_split(vb.y, h1.y, l1.y);
                bf16_split(vb.z, h1.z, l1.z); bf16_split(vb.w, h1.w, l1.w);
            }
            ((ushort4*)aph)[i * 2] = h0;  ((ushort4*)aph)[i * 2 + 1] = h1;
            ((ushort4*)apl)[i * 2] = l0;  ((ushort4*)apl)[i * 2 + 1] = l1;
        } else {
            int j = i - NA8;
            const int conv = j / NB8;
            int j2 = j - conv * NB8;
            const float* w = conv ? w2 : w1;
            unsigned short* bh = conv ? b2h : b1h;
            unsigned short* bl = conv ? b2l : b1l;
            const int cg = j2 / 9216;          // 36*64*4
            int r1 = j2 - cg * 9216;
            const int s = r1 / 256;
            int r2 = r1 - s * 256;
            const int rc = r2 >> 2;
            const int p = r2 & 3;
            const int tap = s / 12;
            const int fs = s - tap * 12;
            const int cgk = p ^ ((rc >> 1) & 3);
            const int f0 = fs * 32 + cgk * 8;
            const int h = cg * 64 + rc;
            ushort4 hv0, hv1, lv0, lv1;
            unsigned short th, tl;
#define WSPLIT(E, DH, DL) bf16_split(w[(size_t)(h * F_ + f0 + (E)) * K_ + tap], th, tl); DH = th; DL = tl;
            WSPLIT(0, hv0.x, lv0.x) WSPLIT(1, hv0.y, lv0.y)
            WSPLIT(2, hv0.z, lv0.z) WSPLIT(3, hv0.w, lv0.w)
            WSPLIT(4, hv1.x, lv1.x) WSPLIT(5, hv1.y, lv1.y)
            WSPLIT(6, hv1.z, lv1.z) WSPLIT(7, hv1.w, lv1.w)
#undef WSPLIT
            ((ushort4*)bh)[j2 * 2] = hv0;  ((ushort4*)bh)[j2 * 2 + 1] = hv1;
            ((ushort4*)bl)[j2 * 2] = lv0;  ((ushort4*)bl)[j2 * 2 + 1] = lv1;
        }
    }
}

// ---------------------------------------------------------------------------
// Kernel 3: conv-as-GEMM, split-bf16 MFMA (hh + hl + lh), 64x64 tile, full K.
// R6 skeleton, but: LDS stages A ONLY (3 bufs x 8 KB = 24 KB; 442 MB total
// LDS-read traffic, half of R6) while B FRAGMENTS LOAD DIRECTLY FROM L2
// (packed B = 1.7 MB, L2-resident; coalesced 1 KB wave loads) into a named
// double-buffered register set (X/Y), prefetched one step ahead inside fenced
// regions. Counted vmcnt(KA) guarantees A-in-LDS (VMEM retires in order;
// KA = #VMEM issued after that stage group). Compiler auto-inserts the
// precise wait for the B register loads (normal dataflow).
// ---------------------------------------------------------------------------
typedef __attribute__((address_space(3))) char lds_char;
typedef const __attribute__((address_space(1))) char g_char;

#define GLDS(gsrc, ldst)                                                   \
    __builtin_amdgcn_global_load_lds((g_char*)(gsrc), (lds_char*)(ldst), 16, 0, 0)

// stage A for step S into buf S%3: this wave's 2 chunks (waves 0-1: Ah, 2-3: Al)
#define ST(S) {                                                            \
    const int offp = (((S) % 12) * 66 + (S) / 12) * 64;                    \
    GLDS(asrc0 + offp, smem + ((S) % 3) * 8192 + dst0);                    \
    GLDS(asrc1 + offp, smem + ((S) % 3) * 8192 + dst1);                    \
}

// load B fragments of step S directly from L2 into register set R (X or Y)
#define LDB(S, R) {                                                        \
    R##h0 = *(const bf16x8*)(bsrch + (S) * 4096 + badr0);                  \
    R##h1 = *(const bf16x8*)(bsrch + (S) * 4096 + badr1);                  \
    R##l0 = *(const bf16x8*)(bsrcl + (S) * 4096 + badr0);                  \
    R##l1 = *(const bf16x8*)(bsrcl + (S) * 4096 + badr1);                  \
}

#define MFMA1(A, Bv, MI, NI)                                               \
    acc[MI][NI] = __builtin_amdgcn_mfma_f32_16x16x32_bf16(A, Bv, acc[MI][NI], 0, 0, 0);

#define SB __builtin_amdgcn_sched_barrier(0)

#define STEP(S, KA, DOST, DOLDB, BH0, BH1, BL0, BL1) {                     \
    asm volatile("s_waitcnt vmcnt(" #KA ")" ::: "memory");                 \
    __builtin_amdgcn_s_barrier();                                          \
    const char* bb = smem + ((S) % 3) * 8192;                              \
    bf16x8 ah0 = *(const bf16x8*)(bb + aadr0[(S) / 12]);                   \
    bf16x8 ah1 = *(const bf16x8*)(bb + aadr1[(S) / 12]);                   \
    bf16x8 al0 = *(const bf16x8*)(bb + 4096 + aadr0[(S) / 12]);            \
    bf16x8 al1 = *(const bf16x8*)(bb + 4096 + aadr1[(S) / 12]);            \
    asm volatile("s_waitcnt lgkmcnt(0)" ::: "memory");                     \
    SB;                                                                    \
    __builtin_amdgcn_s_barrier();                                          \
    DOST;                                                                  \
    DOLDB;                                                                 \
    SB;                                                                    \
    __builtin_amdgcn_s_setprio(1);                                         \
    MFMA1(ah0, BH0, 0, 0) MFMA1(ah0, BH1, 0, 1)                            \
    MFMA1(ah1, BH0, 1, 0) MFMA1(ah1, BH1, 1, 1)                            \
    MFMA1(ah0, BL0, 0, 0) MFMA1(ah0, BL1, 0, 1)                            \
    MFMA1(ah1, BL0, 1, 0) MFMA1(ah1, BL1, 1, 1)                            \
    MFMA1(al0, BH0, 0, 0) MFMA1(al0, BH1, 0, 1)                            \
    MFMA1(al1, BH0, 1, 0) MFMA1(al1, BH1, 1, 1)                            \
    __builtin_amdgcn_s_setprio(0);                                         \
}

__global__ __launch_bounds__(256, 3) void k_gemm(
        const unsigned short* __restrict__ Aph,
        const unsigned short* __restrict__ Apl,
        const unsigned short* __restrict__ Bph,
        const unsigned short* __restrict__ Bpl,
        float* __restrict__ C) {
    __shared__ __align__(1024) char smem[24576];   // 3 bufs x 8 KB (A only)
    const int lane = threadIdx.x & 63;
    const int wv = threadIdx.x >> 6;
    const int wr = wv >> 1;                // output quadrant row (0,1)
    const int wc = wv & 1;                 // output quadrant col (0,1)
    const int m = blockIdx.x;              // 64-row block
    const int cg = blockIdx.y;             // 64-col group
    const int r0 = m * 64;
    const int h0 = cg * 64;

    // A staging: waves 0-1 stage Ah chunks {0,1},{2,3}; waves 2-3 stage Al
    const char* aplane = (const char*)((wv < 2) ? Aph : Apl)
                         + (size_t)m * AMBLK + lane * 16;
    const int cid = (wv & 1) * 2;          // chunk pair within plane
    const char* asrc0 = aplane + cid * 1024;
    const char* asrc1 = aplane + (cid + 1) * 1024;
    const int dst0 = ((wv < 2) ? 0 : 4096) + cid * 1024;
    const int dst1 = dst0 + 1024;

    // B direct-from-L2 bases (packed, coalesced 1KB fragment loads)
    const char* bsrch = (const char*)Bph + (size_t)cg * BCG;
    const char* bsrcl = (const char*)Bpl + (size_t)cg * BCG;

    // fragment read offsets (chunk-XOR matches the packed layout)
    const int fr = lane & 15;
    const int fc = lane >> 4;
    const int rowA0 = wr * 32 + fr, rowA1 = rowA0 + 16;
    const int colB0 = wc * 32 + fr, colB1 = colB0 + 16;
    int aadr0[3], aadr1[3];
#pragma unroll
    for (int t = 0; t < 3; ++t) {
        aadr0[t] = rowA0 * 64 + ((fc ^ (((rowA0 + t) >> 1) & 3)) << 4);
        aadr1[t] = rowA1 * 64 + ((fc ^ (((rowA1 + t) >> 1) & 3)) << 4);
    }
    const int badr0 = colB0 * 64 + ((fc ^ ((colB0 >> 1) & 3)) << 4);
    const int badr1 = colB1 * 64 + ((fc ^ ((colB1 >> 1) & 3)) << 4);

    const f32x4 z4 = {0.f, 0.f, 0.f, 0.f};
    f32x4 acc[2][2];
    acc[0][0] = z4; acc[0][1] = z4; acc[1][0] = z4; acc[1][1] = z4;

    bf16x8 Xh0, Xh1, Xl0, Xl1, Yh0, Yh1, Yl0, Yl1;

    // prologue: 3 A-stages in flight (6 gload_lds) + B(0) registers (4 loads)
    ST(0) ST(1) ST(2)
    LDB(0, X)
    SB;

    STEP(0,  8,  ST(3),  LDB(1, Y),  Xh0, Xh1, Xl0, Xl1)
    STEP(1,  12, ST(4),  LDB(2, X),  Yh0, Yh1, Yl0, Yl1)
    STEP(2,  16, ST(5),  LDB(3, Y),  Xh0, Xh1, Xl0, Xl1)
    STEP(3,  16, ST(6),  LDB(4, X),  Yh0, Yh1, Yl0, Yl1)
    STEP(4,  16, ST(7),  LDB(5, Y),  Xh0, Xh1, Xl0, Xl1)
    STEP(5,  16, ST(8),  LDB(6, X),  Yh0, Yh1, Yl0, Yl1)
    STEP(6,  16, ST(9),  LDB(7, Y),  Xh0, Xh1, Xl0, Xl1)
    STEP(7,  16, ST(10), LDB(8, X),  Yh0, Yh1, Yl0, Yl1)
    STEP(8,  16, ST(11), LDB(9, Y),  Xh0, Xh1, Xl0, Xl1)
    STEP(9,  16, ST(12), LDB(10, X), Yh0, Yh1, Yl0, Yl1)
    STEP(10, 16, ST(13), LDB(11, Y), Xh0, Xh1, Xl0, Xl1)
    STEP(11, 16, ST(14), LDB(12, X), Yh0, Yh1, Yl0, Yl1)
    STEP(12, 16, ST(15), LDB(13, Y), Xh0, Xh1, Xl0, Xl1)
    STEP(13, 16, ST(16), LDB(14, X), Yh0, Yh1, Yl0, Yl1)
    STEP(14, 16, ST(17), LDB(15, Y), Xh0, Xh1, Xl0, Xl1)
    STEP(15, 16, ST(18), LDB(16, X), Yh0, Yh1, Yl0, Yl1)
    STEP(16, 16, ST(19), LDB(17, Y), Xh0, Xh1, Xl0, Xl1)
    STEP(17, 16, ST(20), LDB(18, X), Yh0, Yh1, Yl0, Yl1)
    STEP(18, 16, ST(21), LDB(19, Y), Xh0, Xh1, Xl0, Xl1)
    STEP(19, 16, ST(22), LDB(20, X), Yh0, Yh1, Yl0, Yl1)
    STEP(20, 16, ST(23), LDB(21, Y), Xh0, Xh1, Xl0, Xl1)
    STEP(21, 16, ST(24), LDB(22, X), Yh0, Yh1, Yl0, Yl1)
    STEP(22, 16, ST(25), LDB(23, Y), Xh0, Xh1, Xl0, Xl1)
    STEP(23, 16, ST(26), LDB(24, X), Yh0, Yh1, Yl0, Yl1)
    STEP(24, 16, ST(27), LDB(25, Y), Xh0, Xh1, Xl0, Xl1)
    STEP(25, 16, ST(28), LDB(26, X), Yh0, Yh1, Yl0, Yl1)
    STEP(26, 16, ST(29), LDB(27, Y), Xh0, Xh1, Xl0, Xl1)
    STEP(27, 16, ST(30), LDB(28, X), Yh0, Yh1, Yl0, Yl1)
    STEP(28, 16, ST(31), LDB(29, Y), Xh0, Xh1, Xl0, Xl1)
    STEP(29, 16, ST(32), LDB(30, X), Yh0, Yh1, Yl0, Yl1)
    STEP(30, 16, ST(33), LDB(31, Y), Xh0, Xh1, Xl0, Xl1)
    STEP(31, 16, ST(34), LDB(32, X), Yh0, Yh1, Yl0, Yl1)
    STEP(32, 16, ST(35), LDB(33, Y), Xh0, Xh1, Xl0, Xl1)
    STEP(33, 16, (void)0, LDB(34, X), Yh0, Yh1, Yl0, Yl1)
    STEP(34, 14, (void)0, LDB(35, Y), Xh0, Xh1, Xl0, Xl1)
    STEP(35, 12, (void)0, (void)0,    Yh0, Yh1, Yl0, Yl1)

    // direct C write: C/D layout col = lane&15, row = (lane>>4)*4 + reg
    const int rb = (lane >> 4) * 4;
#pragma unroll
    for (int mi = 0; mi < 2; ++mi)
#pragma unroll
        for (int ni = 0; ni < 2; ++ni)
#pragma unroll
            for (int r = 0; r < 4; ++r)
                C[(size_t)(r0 + wr * 32 + mi * 16 + rb + r) * H_ +
                  h0 + wc * 32 + ni * 16 + fr] = acc[mi][ni][r];
}

// ---------------------------------------------------------------------------
// Kernel 4: bias + LayerNorm + ReLU over raw conv1 output, re-split into the
// PACKED A panels (1-2 slots per row; guard rows stay zero from prep).
// ---------------------------------------------------------------------------
__global__ __launch_bounds__(256) void k_lnrelu(
        const float* __restrict__ c, const float* __restrict__ cb,
        const float* __restrict__ g, const float* __restrict__ bt,
        unsigned short* __restrict__ oh, unsigned short* __restrict__ ol) {
    const int row = blockIdx.x * 4 + (threadIdx.x >> 6);
    const int lane = threadIdx.x & 63;
    const float* cr = c + (size_t)row * H_;
    float2 dv[3];
    dv[0] = ((const float2*)cr)[lane];
    dv[1] = ((const float2*)cr)[lane + 64];
    dv[2] = ((const float2*)cr)[lane + 128];
#pragma unroll
    for (int p = 0; p < 3; ++p) {
        const int ch = 2 * (lane + 64 * p);
        dv[p].x += cb[ch];
        dv[p].y += cb[ch + 1];
    }
    float s = dv[0].x + dv[0].y + dv[1].x + dv[1].y + dv[2].x + dv[2].y;
    float s2 = dv[0].x * dv[0].x + dv[0].y * dv[0].y + dv[1].x * dv[1].x
             + dv[1].y * dv[1].y + dv[2].x * dv[2].x + dv[2].y * dv[2].y;
    for (int off = 32; off >= 1; off >>= 1) {
        s += __shfl_xor(s, off);
        s2 += __shfl_xor(s2, off);
    }
    const float mu = s * (1.f / H_);
    const float var = s2 * (1.f / H_) - mu * mu;
    const float rs = rsqrtf(var + EPS_);
    unsigned short hv[6], lv[6];
#pragma unroll
    for (int p = 0; p < 3; ++p) {
        const int ch = 2 * (lane + 64 * p);
        float r0 = fmaxf((dv[p].x - mu) * rs * g[ch] + bt[ch], 0.f);
        float r1 = fmaxf((dv[p].y - mu) * rs * g[ch + 1] + bt[ch + 1], 0.f);
        bf16_split(r0, hv[2 * p], lv[2 * p]);
        bf16_split(r1, hv[2 * p + 1], lv[2 * p + 1]);
    }
#define WSLOT(M, RP) {                                                        \
    _Pragma("unroll")                                                         \
    for (int p = 0; p < 3; ++p) {                                             \
        const int ch = 2 * (lane + 64 * p);                                   \
        const int fs = ch >> 5;                                               \
        const int k32 = ch & 31;                                              \
        const int pst = (k32 >> 3) ^ (((RP) >> 1) & 3);                       \
        const size_t ix = ((size_t)(((M) * 12 + fs) * 66 + (RP)) * 4 + pst) * 8 + (k32 & 7); \
        *(ushort2*)(oh + ix) = make_ushort2(hv[2 * p], hv[2 * p + 1]);        \
        *(ushort2*)(ol + ix) = make_ushort2(lv[2 * p], lv[2 * p + 1]);        \
    }                                                                         \
}
    const int m1 = row >> 6;
    const int rsub = row & 63;
    WSLOT(m1, rsub + 1);
    if (rsub == 0 && (row & 511) != 0)   WSLOT(m1 - 1, 65);
    if (rsub == 63 && (row & 511) != 511) WSLOT(m1 + 1, 0);
#undef WSLOT
}

// ---------------------------------------------------------------------------
// Kernel 5: bias + LayerNorm + ReLU + linear + ReLU + exp -> durations.
// ---------------------------------------------------------------------------
__global__ __launch_bounds__(256) void k_fin(
        const float* __restrict__ c, const float* __restrict__ cb,
        const float* __restrict__ g, const float* __restrict__ bt,
        const float* __restrict__ lw, const float* __restrict__ lb,
        float* __restrict__ dur) {
    const int row = blockIdx.x * 4 + (threadIdx.x >> 6);
    const int lane = threadIdx.x & 63;
    const float* cr = c + (size_t)row * F_;
    float2 dv[3];
    dv[0] = ((const float2*)cr)[lane];
    dv[1] = ((const float2*)cr)[lane + 64];
    dv[2] = ((const float2*)cr)[lane + 128];
#pragma unroll
    for (int p = 0; p < 3; ++p) {
        const int ch = 2 * (lane + 64 * p);
        dv[p].x += cb[ch];
        dv[p].y += cb[ch + 1];
    }
    float s = dv[0].x + dv[0].y + dv[1].x + dv[1].y + dv[2].x + dv[2].y;
    float s2 = dv[0].x * dv[0].x + dv[0].y * dv[0].y + dv[1].x * dv[1].x
             + dv[1].y * dv[1].y + dv[2].x * dv[2].x + dv[2].y * dv[2].y;
    for (int off = 32; off >= 1; off >>= 1) {
        s += __shfl_xor(s, off);
        s2 += __shfl_xor(s2, off);
    }
    const float mu = s * (1.f / F_);
    const float var = s2 * (1.f / F_) - mu * mu;
    const float rs = rsqrtf(var + EPS_);
    float dot = 0.f;
#pragma unroll
    for (int p = 0; p < 3; ++p) {
        const int ch = 2 * (lane + 64 * p);
        float r0 = fmaxf((dv[p].x - mu) * rs * g[ch] + bt[ch], 0.f);
        float r1 = fmaxf((dv[p].y - mu) * rs * g[ch + 1] + bt[ch + 1], 0.f);
        dot += r0 * lw[ch] + r1 * lw[ch + 1];
    }
    for (int off = 32; off >= 1; off >>= 1) dot += __shfl_xor(dot, off);
    if (lane == 0) dur[row] = expf(fmaxf(dot + lb[0], 0.f));
}

// ---------------------------------------------------------------------------
// Kernel 6: length-regulate gather (memory bound, unchanged).
// ---------------------------------------------------------------------------
__global__ void k_gather(const float4* __restrict__ x, const int* __restrict__ idx,
                         float4* __restrict__ out) {
    const int F4 = F_ / 4;                        // 96
    const int total = B_ * MAX_OUT_ * F4;
    for (int i = blockIdx.x * blockDim.x + threadIdx.x; i < total;
         i += gridDim.x * blockDim.x) {
        int row = i / F4;
        int f4 = i - row * F4;
        int t = row % MAX_OUT_;
        int b = row / MAX_OUT_;
        int id = idx[b * MAX_OUT_ + t];
        float4 v = make_float4(0.f, 0.f, 0.f, 0.f);
        if (id >= 0) v = x[((size_t)b * L_ + id) * F4 + f4];
        out[i] = v;
    }
}

// ---------------------------------------------------------------------------
extern "C" void kernel_launch(void* const* d_in, const int* in_sizes, int n_in,
                              void* d_out, int out_size, void* d_ws, size_t ws_size,
                              hipStream_t stream) {
    const float* input   = (const float*)d_in[0];
    const int*   target  = (const int*)d_in[1];
    const float* conv1_w = (const float*)d_in[2];
    const float* conv1_b = (const float*)d_in[3];
    const float* ln1_g   = (const float*)d_in[4];
    const float* ln1_b   = (const float*)d_in[5];
    const float* conv2_w = (const float*)d_in[6];
    const float* conv2_b = (const float*)d_in[7];
    const float* ln2_g   = (const float*)d_in[8];
    const float* ln2_b   = (const float*)d_in[9];
    const float* lin_w   = (const float*)d_in[10];
    const float* lin_b   = (const float*)d_in[11];

    float* out0 = (float*)d_out;                                  // [B, 4096, F]
    float* dur  = out0 + (size_t)B_ * MAX_OUT_ * F_;              // [B, L]
    float* c    = out0;   // raw conv outputs [8192][384] f32 (overwritten by gather)
    // Big A packs live in d_out's unused tail (everything below dur is
    // overwritten by the final gather).
    char* ob = (char*)d_out;
    unsigned short* aph = (unsigned short*)(ob + (16u << 20));    // 6.49MB
    unsigned short* apl = (unsigned short*)(ob + (24u << 20));    // 6.49MB

    // workspace: idx 256KB + B packs 3.54MB
    char* ws = (char*)d_ws;
    int* idx = (int*)ws;                                          // 262144 B
    unsigned short* b1h = (unsigned short*)(ws + 262144);
    unsigned short* b1l = b1h + BPLANE / 2;
    unsigned short* b2h = b1l + BPLANE / 2;
    unsigned short* b2l = b2h + BPLANE / 2;

    hipLaunchKernelGGL(k_scan_idx, dim3(B_), dim3(L_), 0, stream, target, idx);
    hipLaunchKernelGGL(k_prep, dim3(2048), dim3(256), 0, stream,
                       input, conv1_w, conv2_w, aph, apl, b1h, b1l, b2h, b2l);
    // conv1: raw output into out0 scratch
    hipLaunchKernelGGL(k_gemm, dim3(NMB, NCG), dim3(256), 0, stream,
                       aph, apl, b1h, b1l, c);
    // bias+LN+ReLU, re-split into the packed A panels (guards stay zero)
    hipLaunchKernelGGL(k_lnrelu, dim3(M_TOTAL / 4), dim3(256), 0, stream,
                       c, conv1_b, ln1_g, ln1_b, aph, apl);
    // conv2: raw output into out0 scratch
    hipLaunchKernelGGL(k_gemm, dim3(NMB, NCG), dim3(256), 0, stream,
                       aph, apl, b2h, b2l, c);
    // bias+LN+ReLU+linear+ReLU+exp -> durations
    hipLaunchKernelGGL(k_fin, dim3(M_TOTAL / 4), dim3(256), 0, stream,
                       c, conv2_b, ln2_g, ln2_b, lin_w, lin_b, dur);
    // finally overwrite out0 with the gather
    hipLaunchKernelGGL(k_gather, dim3(4096), dim3(256), 0, stream,
                       (const float4*)input, idx, (float4*)out0);
}

// Round 8
// 89.875 us; speedup vs baseline: 1.1927x; 1.1927x over previous
//
#include <hip/hip_runtime.h>
#include <math.h>

// Problem constants
#define B_ 16
#define L_ 512
#define F_ 384
#define H_ 384
#define K_ 3
#define MAX_OUT_ 4096
#define EPS_ 1e-5f

#define M_TOTAL (B_ * L_)             // 8192 gemm rows
#define KDIM (K_ * F_)                // 1152 gemm K
#define NMB 128                       // 64-row blocks (8192/64)
#define NCG 6                         // 64-col groups (384/64)
#define NST 36                        // K-steps of 32 (1152/32)
// Apack: [m(128)][fstep(12)][row(66)][64B]  (row r -> global l = m*64 + r - 1)
#define APANEL (66 * 64)              // bytes per fstep panel = 4224
#define AMBLK (12 * APANEL)           // bytes per m block = 50688
#define APLANE (NMB * AMBLK)          // 6488064 B per plane
// Bpack: [cg(6)][step(36)][row(64)][64B]
#define BSTEP 4096
#define BCG (NST * BSTEP)             // 147456
#define BPLANE (NCG * BCG)            // 884736 B per plane

typedef __attribute__((ext_vector_type(8))) short bf16x8;   // 8 bf16 = 4 VGPR
typedef __attribute__((ext_vector_type(4))) float f32x4;

// ---------------------------------------------------------------------------
// bf16 split helpers: v = hi + lo with RNE rounding (3-term product error ~2^-17)
// ---------------------------------------------------------------------------
__device__ inline unsigned short bf16_rne(float v) {
    unsigned int u = __float_as_uint(v);
    unsigned int r = (u + 0x7fffu + ((u >> 16) & 1u)) >> 16;
    return (unsigned short)r;
}
__device__ inline void bf16_split(float v, unsigned short& hi, unsigned short& lo) {
    hi = bf16_rne(v);
    float hf = __uint_as_float(((unsigned int)hi) << 16);
    lo = bf16_rne(v - hf);
}

// ---------------------------------------------------------------------------
// Kernel 1: merged scan + prep.
// Blocks 0..15: per-batch cumsum of target + searchsorted index table.
// Blocks 16.. : build LANE-CONTIGUOUS packed operand panels (the LDS image)
// with the chunk permutation p_store = chunk ^ ((row>>1)&3) baked in.
// ---------------------------------------------------------------------------
__global__ void k_scan_prep(const int* __restrict__ target, int* __restrict__ idx,
                            const float* __restrict__ x,
                            const float* __restrict__ w1, const float* __restrict__ w2,
                            unsigned short* __restrict__ aph, unsigned short* __restrict__ apl,
                            unsigned short* __restrict__ b1h, unsigned short* __restrict__ b1l,
                            unsigned short* __restrict__ b2h, unsigned short* __restrict__ b2l) {
    if (blockIdx.x < 16) {
        __shared__ int e[L_];
        const int b = blockIdx.x;
        const int tid = threadIdx.x;   // blockDim = 512 = L_
        e[tid] = target[b * L_ + tid];
        __syncthreads();
        for (int off = 1; off < L_; off <<= 1) {
            int add = (tid >= off) ? e[tid - off] : 0;
            __syncthreads();
            e[tid] += add;
            __syncthreads();
        }
        const int total = e[L_ - 1];
        for (int t = tid; t < MAX_OUT_; t += L_) {
            int lo = 0, hi = L_;
            while (lo < hi) {
                int m = (lo + hi) >> 1;
                if (e[m] <= t) lo = m + 1; else hi = m;
            }
            int v = (t < total) ? min(lo, L_ - 1) : -1;
            idx[b * MAX_OUT_ + t] = v;
        }
        return;
    }
    const int NA8 = NMB * 12 * 66 * 4;     // 405504 A chunks (16B each)
    const int NB8 = NCG * NST * 64 * 4;    // 55296 B chunks per conv
    const int total = NA8 + 2 * NB8;
    for (int i = (blockIdx.x - 16) * blockDim.x + threadIdx.x; i < total;
         i += (gridDim.x - 16) * blockDim.x) {
        if (i < NA8) {
            const int m = i / 3168;            // 12*66*4
            int r1 = i - m * 3168;
            const int fs = r1 / 264;           // 66*4
            int r2 = r1 - fs * 264;
            const int rp = r2 >> 2;
            const int p = r2 & 3;
            const int cgk = p ^ ((rp >> 1) & 3);
            const int f0 = fs * 32 + cgk * 8;
            const int ll = ((m & 7) << 6) + rp - 1;
            ushort4 h0 = {0,0,0,0}, h1 = {0,0,0,0}, l0 = {0,0,0,0}, l1 = {0,0,0,0};
            if (ll >= 0 && ll < L_) {
                const float* src = x + ((size_t)((m >> 3) * L_ + ll) * F_ + f0);
                float4 va = ((const float4*)src)[0];
                float4 vb = ((const float4*)src)[1];
                bf16_split(va.x, h0.x, l0.x); bf16_split(va.y, h0.y, l0.y);
                bf16_split(va.z, h0.z, l0.z); bf16_split(va.w, h0.w, l0.w);
                bf16_split(vb.x, h1.x, l1.x); bf16_split(vb.y, h1.y, l1.y);
                bf16_split(vb.z, h1.z, l1.z); bf16_split(vb.w, h1.w, l1.w);
            }
            ((ushort4*)aph)[i * 2] = h0;  ((ushort4*)aph)[i * 2 + 1] = h1;
            ((ushort4*)apl)[i * 2] = l0;  ((ushort4*)apl)[i * 2 + 1] = l1;
        } else {
            int j = i - NA8;
            const int conv = j / NB8;
            int j2 = j - conv * NB8;
            const float* w = conv ? w2 : w1;
            unsigned short* bh = conv ? b2h : b1h;
            unsigned short* bl = conv ? b2l : b1l;
            const int cg = j2 / 9216;          // 36*64*4
            int r1 = j2 - cg * 9216;
            const int s = r1 / 256;
            int r2 = r1 - s * 256;
            const int rc = r2 >> 2;
            const int p = r2 & 3;
            const int tap = s / 12;
            const int fs = s - tap * 12;
            const int cgk = p ^ ((rc >> 1) & 3);
            const int f0 = fs * 32 + cgk * 8;
            const int h = cg * 64 + rc;
            ushort4 hv0, hv1, lv0, lv1;
            unsigned short th, tl;
#define WSPLIT(E, DH, DL) bf16_split(w[(size_t)(h * F_ + f0 + (E)) * K_ + tap], th, tl); DH = th; DL = tl;
            WSPLIT(0, hv0.x, lv0.x) WSPLIT(1, hv0.y, lv0.y)
            WSPLIT(2, hv0.z, lv0.z) WSPLIT(3, hv0.w, lv0.w)
            WSPLIT(4, hv1.x, lv1.x) WSPLIT(5, hv1.y, lv1.y)
            WSPLIT(6, hv1.z, lv1.z) WSPLIT(7, hv1.w, lv1.w)
#undef WSPLIT
            ((ushort4*)bh)[j2 * 2] = hv0;  ((ushort4*)bh)[j2 * 2 + 1] = hv1;
            ((ushort4*)bl)[j2 * 2] = lv0;  ((ushort4*)bl)[j2 * 2 + 1] = lv1;
        }
    }
}

// ---------------------------------------------------------------------------
// Kernel 2: conv-as-GEMM, split-bf16 MFMA (hh + hl + lh), 64x64 tile, full K.
// R6 structure (proven 101.8us) with ONE barrier per K-step: stage-2-ahead
// means ST(S+2) writes buf (S+2)%3, disjoint from the read buf S%3, and the
// top-of-step barrier already separates last step's (retired) ds_reads from
// this step's gload_lds writes. vmcnt(4) = one stage group in flight.
// ---------------------------------------------------------------------------
typedef __attribute__((address_space(3))) char lds_char;
typedef const __attribute__((address_space(1))) char g_char;

#define GLDS(gsrc, ldst)                                                   \
    __builtin_amdgcn_global_load_lds((g_char*)(gsrc), (lds_char*)(ldst), 16, 0, 0)

// stage step S into buf S%3: this wave's plane, 4 contiguous 1KB loads
#define ST(S) {                                                            \
    const int off = wvA ? ((((S) % 12) * 66 + (S) / 12) * 64) : ((S) * 4096); \
    _Pragma("unroll")                                                      \
    for (int q = 0; q < 4; ++q)                                            \
        GLDS(srcbase + off + q * 1024,                                     \
             smem + ((S) % 3) * 16384 + wvoff + q * 1024);                 \
}

#define MFMA1(A, Bv, MI, NI)                                               \
    acc[MI][NI] = __builtin_amdgcn_mfma_f32_16x16x32_bf16(A, Bv, acc[MI][NI], 0, 0, 0);

#define STEP(S, NW, DOSTAGE) {                                             \
    asm volatile("s_waitcnt vmcnt(" #NW ")" ::: "memory");                 \
    __builtin_amdgcn_s_barrier();                                          \
    const char* bb = smem + ((S) % 3) * 16384;                             \
    const int tp = (S) / 12;                                               \
    bf16x8 ah0 = *(const bf16x8*)(bb + aadr0[tp]);                         \
    bf16x8 ah1 = *(const bf16x8*)(bb + aadr1[tp]);                         \
    bf16x8 al0 = *(const bf16x8*)(bb + 4096 + aadr0[tp]);                  \
    bf16x8 al1 = *(const bf16x8*)(bb + 4096 + aadr1[tp]);                  \
    bf16x8 bh0 = *(const bf16x8*)(bb + 8192 + badr0);                      \
    bf16x8 bh1 = *(const bf16x8*)(bb + 8192 + badr1);                      \
    bf16x8 bl0 = *(const bf16x8*)(bb + 12288 + badr0);                     \
    bf16x8 bl1 = *(const bf16x8*)(bb + 12288 + badr1);                     \
    DOSTAGE;                                                               \
    asm volatile("s_waitcnt lgkmcnt(0)" ::: "memory");                     \
    __builtin_amdgcn_sched_barrier(0);                                     \
    __builtin_amdgcn_s_setprio(1);                                         \
    MFMA1(ah0, bh0, 0, 0) MFMA1(ah0, bh1, 0, 1)                            \
    MFMA1(ah1, bh0, 1, 0) MFMA1(ah1, bh1, 1, 1)                            \
    MFMA1(ah0, bl0, 0, 0) MFMA1(ah0, bl1, 0, 1)                            \
    MFMA1(ah1, bl0, 1, 0) MFMA1(ah1, bl1, 1, 1)                            \
    MFMA1(al0, bh0, 0, 0) MFMA1(al0, bh1, 0, 1)                            \
    MFMA1(al1, bh0, 1, 0) MFMA1(al1, bh1, 1, 1)                            \
    __builtin_amdgcn_s_setprio(0);                                         \
}

__global__ __launch_bounds__(256, 3) void k_gemm(
        const unsigned short* __restrict__ Aph,
        const unsigned short* __restrict__ Apl,
        const unsigned short* __restrict__ Bph,
        const unsigned short* __restrict__ Bpl,
        float* __restrict__ C) {
    __shared__ __align__(1024) char smem[49152];   // 3 bufs x 16 KB
    const int lane = threadIdx.x & 63;
    const int wv = threadIdx.x >> 6;       // wave: stages plane wv
    const int wr = wv >> 1;                // output quadrant row (0,1)
    const int wc = wv & 1;                 // output quadrant col (0,1)
    const int m = blockIdx.x;              // 64-row block
    const int cg = blockIdx.y;             // 64-col group
    const int r0 = m * 64;
    const int h0 = cg * 64;

    const bool wvA = (wv < 2);
    const int wvoff = wv * 4096;
    const char* srcbase;
    {
        const char* ap = (wv == 0) ? (const char*)Aph : (const char*)Apl;
        const char* bp = (wv == 2) ? (const char*)Bph : (const char*)Bpl;
        srcbase = (wvA ? ap + (size_t)m * AMBLK : bp + (size_t)cg * BCG) + lane * 16;
    }

    // fragment read offsets (chunk-XOR matches the packed layout)
    const int fr = lane & 15;
    const int fc = lane >> 4;
    const int rowA0 = wr * 32 + fr, rowA1 = rowA0 + 16;
    const int colB0 = wc * 32 + fr, colB1 = colB0 + 16;
    int aadr0[3], aadr1[3];
#pragma unroll
    for (int t = 0; t < 3; ++t) {
        aadr0[t] = rowA0 * 64 + ((fc ^ (((rowA0 + t) >> 1) & 3)) << 4);
        aadr1[t] = rowA1 * 64 + ((fc ^ (((rowA1 + t) >> 1) & 3)) << 4);
    }
    const int badr0 = colB0 * 64 + ((fc ^ ((colB0 >> 1) & 3)) << 4);
    const int badr1 = colB1 * 64 + ((fc ^ ((colB1 >> 1) & 3)) << 4);

    const f32x4 z4 = {0.f, 0.f, 0.f, 0.f};
    f32x4 acc[2][2];
    acc[0][0] = z4; acc[0][1] = z4; acc[1][0] = z4; acc[1][1] = z4;

    // prologue: 2 stages in flight (8 loads/wave)
    ST(0) ST(1)

    STEP(0, 4, ST(2))   STEP(1, 4, ST(3))   STEP(2, 4, ST(4))
    STEP(3, 4, ST(5))   STEP(4, 4, ST(6))   STEP(5, 4, ST(7))
    STEP(6, 4, ST(8))   STEP(7, 4, ST(9))   STEP(8, 4, ST(10))
    STEP(9, 4, ST(11))  STEP(10, 4, ST(12)) STEP(11, 4, ST(13))
    STEP(12, 4, ST(14)) STEP(13, 4, ST(15)) STEP(14, 4, ST(16))
    STEP(15, 4, ST(17)) STEP(16, 4, ST(18)) STEP(17, 4, ST(19))
    STEP(18, 4, ST(20)) STEP(19, 4, ST(21)) STEP(20, 4, ST(22))
    STEP(21, 4, ST(23)) STEP(22, 4, ST(24)) STEP(23, 4, ST(25))
    STEP(24, 4, ST(26)) STEP(25, 4, ST(27)) STEP(26, 4, ST(28))
    STEP(27, 4, ST(29)) STEP(28, 4, ST(30)) STEP(29, 4, ST(31))
    STEP(30, 4, ST(32)) STEP(31, 4, ST(33)) STEP(32, 4, ST(34))
    STEP(33, 4, ST(35)) STEP(34, 4, )       STEP(35, 0, )

    // direct C write: C/D layout col = lane&15, row = (lane>>4)*4 + reg
    const int rb = (lane >> 4) * 4;
#pragma unroll
    for (int mi = 0; mi < 2; ++mi)
#pragma unroll
        for (int ni = 0; ni < 2; ++ni)
#pragma unroll
            for (int r = 0; r < 4; ++r)
                C[(size_t)(r0 + wr * 32 + mi * 16 + rb + r) * H_ +
                  h0 + wc * 32 + ni * 16 + fr] = acc[mi][ni][r];
}

// ---------------------------------------------------------------------------
// Kernel 3: bias + LayerNorm + ReLU over raw conv1 output, re-split into the
// PACKED A panels (1-2 slots per row; guard rows stay zero from prep).
// ---------------------------------------------------------------------------
__global__ __launch_bounds__(256) void k_lnrelu(
        const float* __restrict__ c, const float* __restrict__ cb,
        const float* __restrict__ g, const float* __restrict__ bt,
        unsigned short* __restrict__ oh, unsigned short* __restrict__ ol) {
    const int row = blockIdx.x * 4 + (threadIdx.x >> 6);
    const int lane = threadIdx.x & 63;
    const float* cr = c + (size_t)row * H_;
    float2 dv[3];
    dv[0] = ((const float2*)cr)[lane];
    dv[1] = ((const float2*)cr)[lane + 64];
    dv[2] = ((const float2*)cr)[lane + 128];
#pragma unroll
    for (int p = 0; p < 3; ++p) {
        const int ch = 2 * (lane + 64 * p);
        dv[p].x += cb[ch];
        dv[p].y += cb[ch + 1];
    }
    float s = dv[0].x + dv[0].y + dv[1].x + dv[1].y + dv[2].x + dv[2].y;
    float s2 = dv[0].x * dv[0].x + dv[0].y * dv[0].y + dv[1].x * dv[1].x
             + dv[1].y * dv[1].y + dv[2].x * dv[2].x + dv[2].y * dv[2].y;
    for (int off = 32; off >= 1; off >>= 1) {
        s += __shfl_xor(s, off);
        s2 += __shfl_xor(s2, off);
    }
    const float mu = s * (1.f / H_);
    const float var = s2 * (1.f / H_) - mu * mu;
    const float rs = rsqrtf(var + EPS_);
    unsigned short hv[6], lv[6];
#pragma unroll
    for (int p = 0; p < 3; ++p) {
        const int ch = 2 * (lane + 64 * p);
        float r0 = fmaxf((dv[p].x - mu) * rs * g[ch] + bt[ch], 0.f);
        float r1 = fmaxf((dv[p].y - mu) * rs * g[ch + 1] + bt[ch + 1], 0.f);
        bf16_split(r0, hv[2 * p], lv[2 * p]);
        bf16_split(r1, hv[2 * p + 1], lv[2 * p + 1]);
    }
#define WSLOT(M, RP) {                                                        \
    _Pragma("unroll")                                                         \
    for (int p = 0; p < 3; ++p) {                                             \
        const int ch = 2 * (lane + 64 * p);                                   \
        const int fs = ch >> 5;                                               \
        const int k32 = ch & 31;                                              \
        const int pst = (k32 >> 3) ^ (((RP) >> 1) & 3);                       \
        const size_t ix = ((size_t)(((M) * 12 + fs) * 66 + (RP)) * 4 + pst) * 8 + (k32 & 7); \
        *(ushort2*)(oh + ix) = make_ushort2(hv[2 * p], hv[2 * p + 1]);        \
        *(ushort2*)(ol + ix) = make_ushort2(lv[2 * p], lv[2 * p + 1]);        \
    }                                                                         \
}
    const int m1 = row >> 6;
    const int rsub = row & 63;
    WSLOT(m1, rsub + 1);
    if (rsub == 0 && (row & 511) != 0)   WSLOT(m1 - 1, 65);
    if (rsub == 63 && (row & 511) != 511) WSLOT(m1 + 1, 0);
#undef WSLOT
}

// ---------------------------------------------------------------------------
// Kernel 4: merged fin + gather. Blocks 0..2047 first compute durations for
// their 4 rows (c now lives in workspace, so no aliasing with out0), then all
// 4096 blocks do the length-regulate gather (write-BW bound).
// ---------------------------------------------------------------------------
__global__ __launch_bounds__(256) void k_fin_gather(
        const float* __restrict__ c, const float* __restrict__ cb,
        const float* __restrict__ g, const float* __restrict__ bt,
        const float* __restrict__ lw, const float* __restrict__ lb,
        float* __restrict__ dur,
        const float4* __restrict__ x, const int* __restrict__ idx,
        float4* __restrict__ out) {
    if (blockIdx.x < 2048) {
        const int row = blockIdx.x * 4 + (threadIdx.x >> 6);
        const int lane = threadIdx.x & 63;
        const float* cr = c + (size_t)row * F_;
        float2 dv[3];
        dv[0] = ((const float2*)cr)[lane];
        dv[1] = ((const float2*)cr)[lane + 64];
        dv[2] = ((const float2*)cr)[lane + 128];
#pragma unroll
        for (int p = 0; p < 3; ++p) {
            const int ch = 2 * (lane + 64 * p);
            dv[p].x += cb[ch];
            dv[p].y += cb[ch + 1];
        }
        float s = dv[0].x + dv[0].y + dv[1].x + dv[1].y + dv[2].x + dv[2].y;
        float s2 = dv[0].x * dv[0].x + dv[0].y * dv[0].y + dv[1].x * dv[1].x
                 + dv[1].y * dv[1].y + dv[2].x * dv[2].x + dv[2].y * dv[2].y;
        for (int off = 32; off >= 1; off >>= 1) {
            s += __shfl_xor(s, off);
            s2 += __shfl_xor(s2, off);
        }
        const float mu = s * (1.f / F_);
        const float var = s2 * (1.f / F_) - mu * mu;
        const float rs = rsqrtf(var + EPS_);
        float dot = 0.f;
#pragma unroll
        for (int p = 0; p < 3; ++p) {
            const int ch = 2 * (lane + 64 * p);
            float r0 = fmaxf((dv[p].x - mu) * rs * g[ch] + bt[ch], 0.f);
            float r1 = fmaxf((dv[p].y - mu) * rs * g[ch + 1] + bt[ch + 1], 0.f);
            dot += r0 * lw[ch] + r1 * lw[ch + 1];
        }
        for (int off = 32; off >= 1; off >>= 1) dot += __shfl_xor(dot, off);
        if (lane == 0) dur[row] = expf(fmaxf(dot + lb[0], 0.f));
    }
    const int F4 = F_ / 4;                        // 96
    const int total = B_ * MAX_OUT_ * F4;
    for (int i = blockIdx.x * blockDim.x + threadIdx.x; i < total;
         i += gridDim.x * blockDim.x) {
        int row = i / F4;
        int f4 = i - row * F4;
        int t = row % MAX_OUT_;
        int b = row / MAX_OUT_;
        int id = idx[b * MAX_OUT_ + t];
        float4 v = make_float4(0.f, 0.f, 0.f, 0.f);
        if (id >= 0) v = x[((size_t)b * L_ + id) * F4 + f4];
        out[i] = v;
    }
}

// ---------------------------------------------------------------------------
extern "C" void kernel_launch(void* const* d_in, const int* in_sizes, int n_in,
                              void* d_out, int out_size, void* d_ws, size_t ws_size,
                              hipStream_t stream) {
    const float* input   = (const float*)d_in[0];
    const int*   target  = (const int*)d_in[1];
    const float* conv1_w = (const float*)d_in[2];
    const float* conv1_b = (const float*)d_in[3];
    const float* ln1_g   = (const float*)d_in[4];
    const float* ln1_b   = (const float*)d_in[5];
    const float* conv2_w = (const float*)d_in[6];
    const float* conv2_b = (const float*)d_in[7];
    const float* ln2_g   = (const float*)d_in[8];
    const float* ln2_b   = (const float*)d_in[9];
    const float* lin_w   = (const float*)d_in[10];
    const float* lin_b   = (const float*)d_in[11];

    float* out0 = (float*)d_out;                                  // [B, 4096, F]
    float* dur  = out0 + (size_t)B_ * MAX_OUT_ * F_;              // [B, L]
    // Big A packs live in d_out's unused tail (overwritten by final gather).
    char* ob = (char*)d_out;
    unsigned short* aph = (unsigned short*)(ob + (16u << 20));    // 6.49MB
    unsigned short* apl = (unsigned short*)(ob + (24u << 20));    // 6.49MB

    // workspace: idx 256KB + B packs 3.54MB + C scratch 12.58MB = 15.6MB
    char* ws = (char*)d_ws;
    int* idx = (int*)ws;                                          // 262144 B
    unsigned short* b1h = (unsigned short*)(ws + 262144);
    unsigned short* b1l = b1h + BPLANE / 2;
    unsigned short* b2h = b1l + BPLANE / 2;
    unsigned short* b2l = b2h + BPLANE / 2;
    float* c = (float*)(ws + 262144 + 4 * (size_t)BPLANE);        // [8192][384] f32

    // merged scan (blocks 0..15) + prep (blocks 16..1039)
    hipLaunchKernelGGL(k_scan_prep, dim3(1040), dim3(512), 0, stream,
                       target, idx, input, conv1_w, conv2_w,
                       aph, apl, b1h, b1l, b2h, b2l);
    // conv1: raw output into ws scratch
    hipLaunchKernelGGL(k_gemm, dim3(NMB, NCG), dim3(256), 0, stream,
                       aph, apl, b1h, b1l, c);
    // bias+LN+ReLU, re-split into the packed A panels (guards stay zero)
    hipLaunchKernelGGL(k_lnrelu, dim3(M_TOTAL / 4), dim3(256), 0, stream,
                       c, conv1_b, ln1_g, ln1_b, aph, apl);
    // conv2: raw output into ws scratch
    hipLaunchKernelGGL(k_gemm, dim3(NMB, NCG), dim3(256), 0, stream,
                       aph, apl, b2h, b2l, c);
    // merged fin (durations) + gather (overwrites out0)
    hipLaunchKernelGGL(k_fin_gather, dim3(4096), dim3(256), 0, stream,
                       c, conv2_b, ln2_g, ln2_b, lin_w, lin_b, dur,
                       (const float4*)input, idx, (float4*)out0);
}